// Round 12
// baseline (3440.551 us; speedup 1.0000x reference)
//
#include <hip/hip_runtime.h>
#include <math.h>

#define B_   64
#define T_   256
#define NIN  128
#define NH   2048
#define NTHR 512

typedef unsigned int  u32;
typedef unsigned short u16;
typedef unsigned long long u64;
typedef __attribute__((ext_vector_type(8))) short bf16x8;
typedef __attribute__((ext_vector_type(4))) float f32x4;
typedef __attribute__((ext_vector_type(4))) u32   u32x4;

// persist LDS layout (dynamic, 148,992 B)
// NOTE: size kept large ON PURPOSE: 149 KB forces exactly 1 block/CU placement.
// The A_hi/A_lo regions are DEAD after the prologue register-hoist; the per-wave
// spike staging buffer (8 waves x [16][20] u32 = 10,240 B) overlays offset 0.
#define OFF_AHI  0         // u16 [16][2056]   = 65,792  (A_hi col-major, +8 pad)
#define OFF_ALO  65792     // u16 [16][2056]   = 65,792  (A_lo)
#define OFF_CRED 131584    // f32 [2][8][16][17] = 17,408 (K-split partials, ping-pong)
#define SMEM_BYTES 148992

// ws: u32 spkbuf[2][64][128] = 64 KB, zeroed each launch (tag 0 == step -1, spikes 0)

__device__ __forceinline__ u16 f2bf(float f) {
    u32 u = __float_as_uint(f);
    return (u16)((u + 0x7FFFu + ((u >> 16) & 1u)) >> 16);
}
__device__ __forceinline__ float bf2f(u16 h) { return __uint_as_float(((u32)h) << 16); }

// spike(t) <=> tanh(z) > c <=> z > atanh(c); c known at end of step t-1
__device__ __forceinline__ float zthrf_of(float c) {
    if (c >= 1.f)  return  __builtin_inff();   // tanh < 1  -> never spikes
    if (c <= -1.f) return -__builtin_inff();   // tanh > -1 -> always spikes
    return 0.5f * logf((1.f + c) / (1.f - c));
}

// issue the 8-word tagged fetch WITHOUT waiting; WAIT ties the regs through the
// waitcnt so the compiler cannot copy/use pre-completion values (split-asm rule)
#define ISSUE_POLL(s, A_, B_)                                         \
    asm volatile("global_load_dwordx4 %0, %2, off sc1\n\t"            \
                 "global_load_dwordx4 %1, %2, off offset:16 sc1"      \
                 : "=&v"(A_), "=&v"(B_) : "v"(s) : "memory")
#define WAIT_POLL(A_, B_)                                             \
    asm volatile("s_waitcnt vmcnt(0)" : "+v"(A_), "+v"(B_) :: "memory")

// ============ U precompute: U_pre[b][t][col] = 0.5*(x[b,t]@W_in[:,col] + bias[col])
// q-split 2 (w+acc = 64 regs) so 4 blocks/CU fit; cg loop x4. 512 blocks x 32 rows.
__global__ __launch_bounds__(256, 4) void u_init(
    const float* __restrict__ x, const float* __restrict__ W_in,
    const float* __restrict__ bias, float* __restrict__ u_out)
{
    __shared__ float xS[32 * 132];
    const int tid = threadIdx.x, bid = blockIdx.x;
    const int row0 = bid * 32;
    for (int idx = tid; idx < 32 * NIN; idx += 256) {
        int r = idx >> 7, k = idx & 127;
        xS[r * 132 + k] = x[(size_t)(row0 + r) * NIN + k];
    }
    __syncthreads();

    for (int cg = 0; cg < 4; ++cg) {
        const int c0 = cg * 512 + tid;            // and c0+256
        const float b0 = bias[c0], b1 = bias[c0 + 256];
        for (int rg = 0; rg < 2; ++rg) {
            float acc0[16], acc1[16];
#pragma unroll
            for (int r = 0; r < 16; ++r) { acc0[r] = 0.f; acc1[r] = 0.f; }
            for (int kc = 0; kc < 8; ++kc) {
                float w0[16], w1[16];
#pragma unroll
                for (int kk = 0; kk < 16; ++kk) {
                    w0[kk] = W_in[(size_t)(kc * 16 + kk) * NH + c0];
                    w1[kk] = W_in[(size_t)(kc * 16 + kk) * NH + c0 + 256];
                }
#pragma unroll
                for (int r = 0; r < 16; ++r) {
                    const f32x4* xv = (const f32x4*)(xS + (rg * 16 + r) * 132 + kc * 16);
                    float a0 = acc0[r], a1 = acc1[r];
#pragma unroll
                    for (int v = 0; v < 4; ++v) {
                        f32x4 xx = xv[v];
                        a0 = fmaf(xx.x, w0[v * 4 + 0], a0); a1 = fmaf(xx.x, w1[v * 4 + 0], a1);
                        a0 = fmaf(xx.y, w0[v * 4 + 1], a0); a1 = fmaf(xx.y, w1[v * 4 + 1], a1);
                        a0 = fmaf(xx.z, w0[v * 4 + 2], a0); a1 = fmaf(xx.z, w1[v * 4 + 2], a1);
                        a0 = fmaf(xx.w, w0[v * 4 + 3], a0); a1 = fmaf(xx.w, w1[v * 4 + 3], a1);
                    }
                    acc0[r] = a0; acc1[r] = a1;
                }
            }
#pragma unroll
            for (int r = 0; r < 16; ++r) {
                u_out[(size_t)(row0 + rg * 16 + r) * NH + c0]       = 0.5f * (acc0[r] + b0);
                u_out[(size_t)(row0 + rg * 16 + r) * NH + c0 + 256] = 0.5f * (acc1[r] + b1);
            }
        }
    }
}

// ============ persistent per-(batch-group, col-block) recurrence
// Round-8 structure (direct tagged poll + quad dedup via wave-local LDS staging,
// one barrier per step) + SPECULATIVE cross-step prefetch: the payload loads for
// step t+1 are issued right after publish(t); at loop top only a tag check (and
// re-poll on mismatch) remains. For the straggler block that gates the group,
// everyone else's data is already published, so its prefetch is valid on arrival
// and the poll RT vanishes from the serial chain.
__global__ __launch_bounds__(NTHR, 2) void persist(
    const float* __restrict__ A,
    const float* __restrict__ mem0,
    float* __restrict__ out_mem,
    float* out_spk,   // holds U_pre until step t overwrites slot t
    u32* __restrict__ spkbuf)
{
    extern __shared__ char smem[];
    u16*   AhiS = (u16*)(smem + OFF_AHI);
    u16*   AloS = (u16*)(smem + OFF_ALO);
    float* cred = (float*)(smem + OFF_CRED);

    const int tid = threadIdx.x;
    const int bid = blockIdx.x;      // 0..255
    const int cb  = bid & 127;       // col-block (16 cols)
    const int bg  = bid >> 7;        // batch group (32 batches)
    const int c0  = cb * 16;

    // A slice -> split-bf16 LDS (exact: a == hi + lo to fp32 round)
    for (int idx = tid; idx < NH * 16; idx += NTHR) {
        int i = idx >> 4, c = idx & 15;
        float a = A[(size_t)i * NH + c0 + c];
        u16 hi = f2bf(a);
        AhiS[c * 2056 + i] = hi;
        AloS[c * 2056 + i] = f2bf(a - bf2f(hi));
    }

    const int n   = tid & 15;        // col within block
    const int bl  = tid >> 4;        // local batch 0..31
    const int b   = bg * 32 + bl;
    const int col = c0 + n;
    double m = (double)mem0[(size_t)b * NH + col];
    double sprev = 0.0;
    float zthrf = zthrf_of((float)(1.0 - 0.5 * m));   // threshold for step 0

    const int lane = tid & 63, wave = tid >> 6;
    const int qn = lane & 15, quad = lane >> 4;
    const int mt = wave & 1;         // M-tile (batches mt*16..+16)
    const int kp = wave >> 1;        // K-partial 0..3
    const u32 sh = ((u32)(quad & 1) * 8) + ((u32)(quad >> 1) * 16);

    float up = out_spk[(size_t)b * T_ * NH + col];   // U_pre(0)

    // per-wave staging region: [16 rows][20 u32] (20 = 16 payload + pad, keeps
    // b128 alignment; rows r,r+8 alias banks 2-way = free)
    u32* stgW = (u32*)smem + wave * 320;

    // this lane's UNIQUE poll slice: row lane>>2, words kp*32 + (lane&3)*8 ..+8
    const u32* pollbase = spkbuf
        + (size_t)(bg * 32 + mt * 16 + (lane >> 2)) * 128 + kp * 32 + (lane & 3) * 8;

    __syncthreads();

    // ---- hoist this wave's step-invariant A fragments into registers (128 VGPRs)
    bf16x8 Ah[16], Al[16];
#pragma unroll
    for (int ktl = 0; ktl < 16; ++ktl) {
        int kt = kp * 16 + ktl;
        Ah[ktl] = *(const bf16x8*)(AhiS + qn * 2056 + quad * 8 + kt * 32);
        Al[ktl] = *(const bf16x8*)(AloS + qn * 2056 + quad * 8 + kt * 32);
    }
    // pin: ds_reads are rematerializable; without this the compiler sinks them
    // back into the t-loop (round-3 VGPR_Count=88 proved it)
#pragma unroll
    for (int i = 0; i < 16; ++i)
        asm volatile("" : "+v"(Ah[i]), "+v"(Al[i]));

    __syncthreads();   // A LDS region is dead from here; staging may overlay it

    // ---- prologue: issue speculative fetch for step 0 (parity 0)
    const u32* src = pollbase;
    u32x4 da, db;
    ISSUE_POLL(src, da, db);

    for (int t = 0; t < T_; ++t) {
        const u32 te = (u32)t << 16;

        // ---- check speculative data; re-poll only on tag mismatch
        WAIT_POLL(da, db);
        u32 bad = (da.x ^ te) | (da.y ^ te) | (da.z ^ te) | (da.w ^ te)
                | (db.x ^ te) | (db.y ^ te) | (db.z ^ te) | (db.w ^ te);
        int guard = 0;
        while (bad >> 16) {
            if (++guard > 30000) break;             // failsafe: no hang
            if (guard > 2) __builtin_amdgcn_s_sleep(1);
            ISSUE_POLL(src, da, db);
            WAIT_POLL(da, db);
            bad = (da.x ^ te) | (da.y ^ te) | (da.z ^ te) | (da.w ^ te)
                | (db.x ^ te) | (db.y ^ te) | (db.z ^ te) | (db.w ^ te);
        }

        // prefetch next step's U_pre AFTER poll (never outstanding at WAIT_POLL)
        float upn = 0.f;
        if (t + 1 < T_) upn = out_spk[((size_t)b * T_ + t + 1) * NH + col];

        // pack payloads (2 u16 -> 1 u32) and stage; wave-lockstep redistribute
        u32x4 pk;
        pk.x = (da.x & 0xFFFFu) | (da.y << 16);
        pk.y = (da.z & 0xFFFFu) | (da.w << 16);
        pk.z = (db.x & 0xFFFFu) | (db.y << 16);
        pk.w = (db.z & 0xFFFFu) | (db.w << 16);
        *(u32x4*)(stgW + (lane >> 2) * 20 + (lane & 3) * 4) = pk;
        asm volatile("s_waitcnt lgkmcnt(0)" ::: "memory");  // write->read, same wave

        u32 sw[16];
        {
            const u32x4* rp = (const u32x4*)(stgW + qn * 20);
            u32x4 s0 = rp[0], s1 = rp[1], s2 = rp[2], s3 = rp[3];
            sw[0] = s0.x; sw[1] = s0.y; sw[2]  = s0.z; sw[3]  = s0.w;
            sw[4] = s1.x; sw[5] = s1.y; sw[6]  = s1.z; sw[7]  = s1.w;
            sw[8] = s2.x; sw[9] = s2.y; sw[10] = s2.z; sw[11] = s2.w;
            sw[12] = s3.x; sw[13] = s3.y; sw[14] = s3.z; sw[15] = s3.w;
        }

        // ---- r = S @ (A_hi + A_lo): 16x16x32 MFMA, 4 independent acc chains
        // (dependent chain depth 32 -> 8; compiler interleaves the chains)
        f32x4 ac0 = {0.f,0.f,0.f,0.f}, ac1 = {0.f,0.f,0.f,0.f};
        f32x4 ac2 = {0.f,0.f,0.f,0.f}, ac3 = {0.f,0.f,0.f,0.f};
#pragma unroll
        for (int ktl = 0; ktl < 4; ++ktl) {
#pragma unroll
            for (int c = 0; c < 4; ++c) {
                int k = c * 4 + ktl;
                u32 byte = (sw[k] >> sh) & 255u;
                u32x4 aw;
                aw.x = ((byte & 1u)   ? 0x3F80u : 0u) | ((byte & 2u)   ? 0x3F800000u : 0u);
                aw.y = ((byte & 4u)   ? 0x3F80u : 0u) | ((byte & 8u)   ? 0x3F800000u : 0u);
                aw.z = ((byte & 16u)  ? 0x3F80u : 0u) | ((byte & 32u)  ? 0x3F800000u : 0u);
                aw.w = ((byte & 64u)  ? 0x3F80u : 0u) | ((byte & 128u) ? 0x3F800000u : 0u);
                bf16x8 af = __builtin_bit_cast(bf16x8, aw);
                f32x4* ac = (c == 0) ? &ac0 : (c == 1) ? &ac1 : (c == 2) ? &ac2 : &ac3;
                *ac = __builtin_amdgcn_mfma_f32_16x16x32_bf16(af, Ah[k], *ac, 0, 0, 0);
                *ac = __builtin_amdgcn_mfma_f32_16x16x32_bf16(af, Al[k], *ac, 0, 0, 0);
            }
        }
        f32x4 acc = (ac0 + ac1) + (ac2 + ac3);
        float* cw = cred + (t & 1) * 2176;
#pragma unroll
        for (int reg = 0; reg < 4; ++reg)
            cw[((kp * 2 + mt) * 16 + quad * 4 + reg) * 17 + qn] = acc[reg];
        __syncthreads();   // the ONE barrier: cred write -> cred read

        // ---- reduce partials; spike decision via precomputed threshold; publish
        float r = 0.f;
#pragma unroll
        for (int p = 0; p < 4; ++p)
            r += cw[((p * 2 + (bl >> 4)) * 16 + (bl & 15)) * 17 + n];

        float zf = 0.5f * r + up;
        int sp = zf > zthrf;

        u64 bal = __ballot(sp);
        if (n == 0) {
            u32 bits = (u32)((bal >> ((bl & 3) * 16)) & 0xFFFFull);
            u32 val = ((u32)(t + 1) << 16) | bits;
            u32* dst = spkbuf + ((t & 1) ? 0 : 8192) + b * 128 + cb;
            __hip_atomic_store(dst, val, __ATOMIC_RELAXED, __HIP_MEMORY_SCOPE_AGENT);
        }

        // ---- speculative fetch for step t+1 (right after publish; overlaps tail
        // and other blocks' publishes)
        src = pollbase + (((t + 1) & 1) ? 8192 : 0);
        if (t + 1 < T_) ISSUE_POLL(src, da, db);

        // ---- deferred tail (off critical path)
        float y = tanhf(zf);
        m = m * 0.5 - 0.5 * (1.0 - sprev) + (double)y;
        size_t o = ((size_t)b * T_ + t) * NH + col;
        out_mem[o] = (float)m;
        out_spk[o] = sp ? 1.f : 0.f;
        sprev = sp ? 1.0 : 0.0;
        zthrf = zthrf_of((float)(1.0 - 0.5 * m - 0.5 * sprev));
        up = upn;
        // no trailing barrier: next step's cred buffer is the other half (ping-pong);
        // staging reuse is wave-local (lockstep); spkbuf overwrite safety comes from
        // the transitive poll ordering (a block publishes t only after all its
        // waves' polls of t completed). Speculative reads never violate that: they
        // are re-checked, and reads never endanger writes.
    }
}

extern "C" void kernel_launch(void* const* d_in, const int* in_sizes, int n_in,
                              void* d_out, int out_size, void* d_ws, size_t ws_size,
                              hipStream_t stream) {
    const float* x    = (const float*)d_in[0];
    const float* W_in = (const float*)d_in[1];
    const float* A    = (const float*)d_in[2];
    const float* bias = (const float*)d_in[3];
    const float* mem0 = (const float*)d_in[4];

    float* out_mem = (float*)d_out;
    float* out_spk = out_mem + (size_t)B_ * T_ * NH;
    u32*   spkbuf  = (u32*)d_ws;

    (void)hipFuncSetAttribute((const void*)persist,
                              hipFuncAttributeMaxDynamicSharedMemorySize, SMEM_BYTES);

    hipMemsetAsync(spkbuf, 0, 2 * 64 * 128 * sizeof(u32), stream);
    hipLaunchKernelGGL(u_init, dim3(512), dim3(256), 0, stream, x, W_in, bias, out_spk);
    hipLaunchKernelGGL(persist, dim3(256), dim3(NTHR), SMEM_BYTES, stream,
                       A, mem0, out_mem, out_spk, spkbuf);
}

// Round 13
// 1124.285 us; speedup vs baseline: 3.0602x; 3.0602x over previous
//
#include <hip/hip_runtime.h>
#include <math.h>

#define B_   64
#define T_   256
#define NIN  128
#define NH   2048
#define NTHR 512

typedef unsigned int  u32;
typedef unsigned short u16;
typedef unsigned long long u64;
typedef __attribute__((ext_vector_type(8))) short bf16x8;
typedef __attribute__((ext_vector_type(4))) float f32x4;
typedef __attribute__((ext_vector_type(4))) u32   u32x4;

// persist LDS layout (dynamic, 148,992 B)
// NOTE: size kept large ON PURPOSE: 149 KB forces exactly 1 block/CU placement.
// The A_hi/A_lo regions are DEAD after the prologue register-hoist; the per-wave
// spike staging buffer (8 waves x [16][20] u32 = 10,240 B) overlays offset 0.
#define OFF_AHI  0         // u16 [16][2056]   = 65,792  (A_hi col-major, +8 pad)
#define OFF_ALO  65792     // u16 [16][2056]   = 65,792  (A_lo)
#define OFF_CRED 131584    // f32 [2][8][16][17] = 17,408 (K-split partials, ping-pong)
#define SMEM_BYTES 148992

// ws: u32 spkbuf[2][64][128] = 64 KB, zeroed each launch (tag 0 == step -1, spikes 0)
//
// LESSON (round 12, measured): do NOT speculatively prefetch the next step's
// payload right after publish — the reads land mid-publish-window and contend
// with 16 publishers/line agent-scope stores; persist went 1010 -> 2920 us and
// FETCH_SIZE doubled. Poll must be issued only at loop top (post-barrier), where
// round 8 measured 1010 us.

__device__ __forceinline__ u16 f2bf(float f) {
    u32 u = __float_as_uint(f);
    return (u16)((u + 0x7FFFu + ((u >> 16) & 1u)) >> 16);
}
__device__ __forceinline__ float bf2f(u16 h) { return __uint_as_float(((u32)h) << 16); }

// spike(t) <=> tanh(z) > c <=> z > atanh(c); c known at end of step t-1
__device__ __forceinline__ float zthrf_of(float c) {
    if (c >= 1.f)  return  __builtin_inff();   // tanh < 1  -> never spikes
    if (c <= -1.f) return -__builtin_inff();   // tanh > -1 -> always spikes
    return 0.5f * logf((1.f + c) / (1.f - c));
}

// ============ U precompute: U_pre[b][t][col] = 0.5*(x[b,t]@W_in[:,col] + bias[col])
// q=4 split: one xS b128 read feeds 16 FMAs (DS-throughput-bound balance point).
// LESSON (round 12): q=2 split halves FMAs-per-DS-read -> u_init ~300 -> ~520 us.
__global__ __launch_bounds__(256, 2) void u_init(
    const float* __restrict__ x, const float* __restrict__ W_in,
    const float* __restrict__ bias, float* __restrict__ u_out)
{
    __shared__ float xS[32 * 132];
    const int tid = threadIdx.x, bid = blockIdx.x;
    const int row0 = bid * 32;
    for (int idx = tid; idx < 32 * NIN; idx += 256) {
        int r = idx >> 7, k = idx & 127;
        xS[r * 132 + k] = x[(size_t)(row0 + r) * NIN + k];
    }
    __syncthreads();

    float bc[4][2];
#pragma unroll
    for (int cg = 0; cg < 2; ++cg)
#pragma unroll
        for (int q = 0; q < 4; ++q)
            bc[q][cg] = bias[cg * 1024 + q * 256 + tid];

    for (int cg = 0; cg < 2; ++cg) {
        for (int rg = 0; rg < 2; ++rg) {
            float acc[4][16];
#pragma unroll
            for (int q = 0; q < 4; ++q)
#pragma unroll
                for (int r = 0; r < 16; ++r) acc[q][r] = 0.f;
            for (int kc = 0; kc < 8; ++kc) {
                float w[4][16];
#pragma unroll
                for (int q = 0; q < 4; ++q)
#pragma unroll
                    for (int kk = 0; kk < 16; ++kk)
                        w[q][kk] = W_in[(size_t)(kc * 16 + kk) * NH + cg * 1024 + q * 256 + tid];
#pragma unroll
                for (int r = 0; r < 16; ++r) {
                    const f32x4* xv = (const f32x4*)(xS + (rg * 16 + r) * 132 + kc * 16);
#pragma unroll
                    for (int v = 0; v < 4; ++v) {
                        f32x4 xx = xv[v];
#pragma unroll
                        for (int q = 0; q < 4; ++q) {
                            acc[q][r] = fmaf(xx.x, w[q][v * 4 + 0], acc[q][r]);
                            acc[q][r] = fmaf(xx.y, w[q][v * 4 + 1], acc[q][r]);
                            acc[q][r] = fmaf(xx.z, w[q][v * 4 + 2], acc[q][r]);
                            acc[q][r] = fmaf(xx.w, w[q][v * 4 + 3], acc[q][r]);
                        }
                    }
                }
            }
#pragma unroll
            for (int r = 0; r < 16; ++r)
#pragma unroll
                for (int q = 0; q < 4; ++q)
                    u_out[(size_t)(row0 + rg * 16 + r) * NH + cg * 1024 + q * 256 + tid]
                        = 0.5f * (acc[q][r] + bc[q][cg]);
        }
    }
}

// ============ persistent per-(batch-group, col-block) recurrence
// Round-8 structure (measured 1010 us): direct tagged poll AT LOOP TOP + quad
// dedup via wave-local LDS staging, one barrier per step. Each wave fetches only
// its UNIQUE 2 KB payload slice (lane l: row lane>>2, word-group lane&3), then
// redistributes within the wave (ds_write_b128 -> lgkmcnt(0) -> 4x ds_read_b128,
// wave-lockstep, no barrier). Kept from round 12: 4 independent MFMA acc chains;
// upn prefetch after the poll (never outstanding at the poll's vmcnt(0)).
__global__ __launch_bounds__(NTHR, 2) void persist(
    const float* __restrict__ A,
    const float* __restrict__ mem0,
    float* __restrict__ out_mem,
    float* out_spk,   // holds U_pre until step t overwrites slot t
    u32* __restrict__ spkbuf)
{
    extern __shared__ char smem[];
    u16*   AhiS = (u16*)(smem + OFF_AHI);
    u16*   AloS = (u16*)(smem + OFF_ALO);
    float* cred = (float*)(smem + OFF_CRED);

    const int tid = threadIdx.x;
    const int bid = blockIdx.x;      // 0..255
    const int cb  = bid & 127;       // col-block (16 cols)
    const int bg  = bid >> 7;        // batch group (32 batches)
    const int c0  = cb * 16;

    // A slice -> split-bf16 LDS (exact: a == hi + lo to fp32 round)
    for (int idx = tid; idx < NH * 16; idx += NTHR) {
        int i = idx >> 4, c = idx & 15;
        float a = A[(size_t)i * NH + c0 + c];
        u16 hi = f2bf(a);
        AhiS[c * 2056 + i] = hi;
        AloS[c * 2056 + i] = f2bf(a - bf2f(hi));
    }

    const int n   = tid & 15;        // col within block
    const int bl  = tid >> 4;        // local batch 0..31
    const int b   = bg * 32 + bl;
    const int col = c0 + n;
    double m = (double)mem0[(size_t)b * NH + col];
    double sprev = 0.0;
    float zthrf = zthrf_of((float)(1.0 - 0.5 * m));   // threshold for step 0

    const int lane = tid & 63, wave = tid >> 6;
    const int qn = lane & 15, quad = lane >> 4;
    const int mt = wave & 1;         // M-tile (batches mt*16..+16)
    const int kp = wave >> 1;        // K-partial 0..3
    const u32 sh = ((u32)(quad & 1) * 8) + ((u32)(quad >> 1) * 16);

    float up = out_spk[(size_t)b * T_ * NH + col];   // U_pre(0)

    // per-wave staging region: [16 rows][20 u32] (20 = 16 payload + pad, keeps
    // b128 alignment; rows r,r+8 alias banks 2-way = free)
    u32* stgW = (u32*)smem + wave * 320;

    // this lane's UNIQUE poll slice: row lane>>2, words kp*32 + (lane&3)*8 ..+8
    const u32* pollbase = spkbuf
        + (size_t)(bg * 32 + mt * 16 + (lane >> 2)) * 128 + kp * 32 + (lane & 3) * 8;

    __syncthreads();

    // ---- hoist this wave's step-invariant A fragments into registers (128 VGPRs)
    bf16x8 Ah[16], Al[16];
#pragma unroll
    for (int ktl = 0; ktl < 16; ++ktl) {
        int kt = kp * 16 + ktl;
        Ah[ktl] = *(const bf16x8*)(AhiS + qn * 2056 + quad * 8 + kt * 32);
        Al[ktl] = *(const bf16x8*)(AloS + qn * 2056 + quad * 8 + kt * 32);
    }
    // pin: ds_reads are rematerializable; without this the compiler sinks them
    // back into the t-loop (round-3 VGPR_Count=88 proved it)
#pragma unroll
    for (int i = 0; i < 16; ++i)
        asm volatile("" : "+v"(Ah[i]), "+v"(Al[i]));

    __syncthreads();   // A LDS region is dead from here; staging may overlay it

    for (int t = 0; t < T_; ++t) {
        // ---- poll own UNIQUE 8 tagged words (2x dwordx4, coherence-point loads)
        // issued ONLY here (post-barrier, late in publish window — see LESSON)
        const u32* src = pollbase + ((t & 1) ? 8192 : 0);
        const u32 te = (u32)t << 16;
        u32x4 da, db;
        int guard = 0;
        while (true) {
            asm volatile(
                "global_load_dwordx4 %0, %2, off sc1\n\t"
                "global_load_dwordx4 %1, %2, off offset:16 sc1\n\t"
                "s_waitcnt vmcnt(0)"
                : "=&v"(da), "=&v"(db)
                : "v"(src)
                : "memory");
            u32 bad = (da.x ^ te) | (da.y ^ te) | (da.z ^ te) | (da.w ^ te)
                    | (db.x ^ te) | (db.y ^ te) | (db.z ^ te) | (db.w ^ te);
            if (!(bad >> 16)) break;                // all 8 tags match (per-lane exit)
            if (++guard > 30000) break;             // failsafe: no hang
            if (guard > 1) __builtin_amdgcn_s_sleep(1);
        }

        // prefetch next step's U_pre AFTER poll (never outstanding at the poll wait)
        float upn = 0.f;
        if (t + 1 < T_) upn = out_spk[((size_t)b * T_ + t + 1) * NH + col];

        // pack payloads (2 u16 -> 1 u32) and stage; wave-lockstep redistribute
        u32x4 pk;
        pk.x = (da.x & 0xFFFFu) | (da.y << 16);
        pk.y = (da.z & 0xFFFFu) | (da.w << 16);
        pk.z = (db.x & 0xFFFFu) | (db.y << 16);
        pk.w = (db.z & 0xFFFFu) | (db.w << 16);
        *(u32x4*)(stgW + (lane >> 2) * 20 + (lane & 3) * 4) = pk;
        asm volatile("s_waitcnt lgkmcnt(0)" ::: "memory");  // write->read, same wave

        u32 sw[16];
        {
            const u32x4* rp = (const u32x4*)(stgW + qn * 20);
            u32x4 s0 = rp[0], s1 = rp[1], s2 = rp[2], s3 = rp[3];
            sw[0] = s0.x; sw[1] = s0.y; sw[2]  = s0.z; sw[3]  = s0.w;
            sw[4] = s1.x; sw[5] = s1.y; sw[6]  = s1.z; sw[7]  = s1.w;
            sw[8] = s2.x; sw[9] = s2.y; sw[10] = s2.z; sw[11] = s2.w;
            sw[12] = s3.x; sw[13] = s3.y; sw[14] = s3.z; sw[15] = s3.w;
        }

        // ---- r = S @ (A_hi + A_lo): 16x16x32 MFMA, 4 independent acc chains
        // (dependent chain depth 32 -> 8; compiler interleaves the chains)
        f32x4 ac0 = {0.f,0.f,0.f,0.f}, ac1 = {0.f,0.f,0.f,0.f};
        f32x4 ac2 = {0.f,0.f,0.f,0.f}, ac3 = {0.f,0.f,0.f,0.f};
#pragma unroll
        for (int ktl = 0; ktl < 4; ++ktl) {
#pragma unroll
            for (int c = 0; c < 4; ++c) {
                int k = c * 4 + ktl;
                u32 byte = (sw[k] >> sh) & 255u;
                u32x4 aw;
                aw.x = ((byte & 1u)   ? 0x3F80u : 0u) | ((byte & 2u)   ? 0x3F800000u : 0u);
                aw.y = ((byte & 4u)   ? 0x3F80u : 0u) | ((byte & 8u)   ? 0x3F800000u : 0u);
                aw.z = ((byte & 16u)  ? 0x3F80u : 0u) | ((byte & 32u)  ? 0x3F800000u : 0u);
                aw.w = ((byte & 64u)  ? 0x3F80u : 0u) | ((byte & 128u) ? 0x3F800000u : 0u);
                bf16x8 af = __builtin_bit_cast(bf16x8, aw);
                f32x4* ac = (c == 0) ? &ac0 : (c == 1) ? &ac1 : (c == 2) ? &ac2 : &ac3;
                *ac = __builtin_amdgcn_mfma_f32_16x16x32_bf16(af, Ah[k], *ac, 0, 0, 0);
                *ac = __builtin_amdgcn_mfma_f32_16x16x32_bf16(af, Al[k], *ac, 0, 0, 0);
            }
        }
        f32x4 acc = (ac0 + ac1) + (ac2 + ac3);
        float* cw = cred + (t & 1) * 2176;
#pragma unroll
        for (int reg = 0; reg < 4; ++reg)
            cw[((kp * 2 + mt) * 16 + quad * 4 + reg) * 17 + qn] = acc[reg];
        __syncthreads();   // the ONE barrier: cred write -> cred read

        // ---- reduce partials; spike decision via precomputed threshold; publish
        float r = 0.f;
#pragma unroll
        for (int p = 0; p < 4; ++p)
            r += cw[((p * 2 + (bl >> 4)) * 16 + (bl & 15)) * 17 + n];

        float zf = 0.5f * r + up;
        int sp = zf > zthrf;

        u64 bal = __ballot(sp);
        if (n == 0) {
            u32 bits = (u32)((bal >> ((bl & 3) * 16)) & 0xFFFFull);
            u32 val = ((u32)(t + 1) << 16) | bits;
            u32* dst = spkbuf + ((t & 1) ? 0 : 8192) + b * 128 + cb;
            __hip_atomic_store(dst, val, __ATOMIC_RELAXED, __HIP_MEMORY_SCOPE_AGENT);
        }

        // ---- deferred tail (off critical path; overlaps other blocks' consumption)
        float y = tanhf(zf);
        m = m * 0.5 - 0.5 * (1.0 - sprev) + (double)y;
        size_t o = ((size_t)b * T_ + t) * NH + col;
        out_mem[o] = (float)m;
        out_spk[o] = sp ? 1.f : 0.f;
        sprev = sp ? 1.0 : 0.0;
        zthrf = zthrf_of((float)(1.0 - 0.5 * m - 0.5 * sprev));
        up = upn;
        // no trailing barrier: next step's cred buffer is the other half (ping-pong);
        // staging reuse is wave-local (lockstep); spkbuf overwrite safety comes from
        // the transitive poll ordering (a block publishes t only after all its
        // waves' polls of t completed).
    }
}

extern "C" void kernel_launch(void* const* d_in, const int* in_sizes, int n_in,
                              void* d_out, int out_size, void* d_ws, size_t ws_size,
                              hipStream_t stream) {
    const float* x    = (const float*)d_in[0];
    const float* W_in = (const float*)d_in[1];
    const float* A    = (const float*)d_in[2];
    const float* bias = (const float*)d_in[3];
    const float* mem0 = (const float*)d_in[4];

    float* out_mem = (float*)d_out;
    float* out_spk = out_mem + (size_t)B_ * T_ * NH;
    u32*   spkbuf  = (u32*)d_ws;

    (void)hipFuncSetAttribute((const void*)persist,
                              hipFuncAttributeMaxDynamicSharedMemorySize, SMEM_BYTES);

    hipMemsetAsync(spkbuf, 0, 2 * 64 * 128 * sizeof(u32), stream);
    hipLaunchKernelGGL(u_init, dim3(512), dim3(256), 0, stream, x, W_in, bias, out_spk);
    hipLaunchKernelGGL(persist, dim3(256), dim3(NTHR), SMEM_BYTES, stream,
                       A, mem0, out_mem, out_spk, spkbuf);
}